// Round 2
// baseline (159.649 us; speedup 1.0000x reference)
//
#include <hip/hip_runtime.h>
#include <hip/hip_bf16.h>
#include <type_traits>

#define NB 8192
#define DD 256
#define INV_T (1.0f/0.07f)
#define NSPLIT 16
#define BM 128
#define BN 64
#define CPS (NB/NSPLIT)      // 512 cols per split
#define NITER (CPS/BN)       // 8

typedef __attribute__((ext_vector_type(8))) short s8v;   // 8 bf16
typedef __attribute__((ext_vector_type(4))) float f4v;   // 4 f32 acc
typedef unsigned int u32;
typedef unsigned short u16;

// workspace layout (bytes)
#define OFF_FB   0                                  // bf16 normalized features: 4 MB
#define OFF_HIST (4*1024*1024)
#define OFF_SE   (OFF_HIST + 4096)                  // f32 [NSPLIT][NB] = 512 KB
#define OFF_SP   (OFF_SE + NSPLIT*NB*4)             // f32 [NSPLIT][NB] = 512 KB
#define OFF_CL   (OFF_SP + NSPLIT*NB*4)             // f32[32]
#define OFF_CV   (OFF_CL + 256)                     // f32[32]

__global__ void k_zero(int* __restrict__ hist) {
    hist[threadIdx.x] = 0;
}

// wave-per-row normalize: grid 2048 x 256 threads (4 waves = 4 rows/block)
__global__ void k_norm(const float* __restrict__ feat, const int* __restrict__ lab,
                       __hip_bfloat16* __restrict__ fb, int* __restrict__ hist) {
    const int t = threadIdx.x;
    const int w = t >> 6, l = t & 63;
    const int row = blockIdx.x * 4 + w;
    const float4 v = ((const float4*)feat)[row * 64 + l];
    float s = v.x * v.x + v.y * v.y + v.z * v.z + v.w * v.w;
    #pragma unroll
    for (int d = 32; d; d >>= 1) s += __shfl_xor(s, d, 64);
    const float scale = 1.0f / fmaxf(sqrtf(s), 1e-12f);
    __hip_bfloat16 h0 = __float2bfloat16(v.x * scale);
    __hip_bfloat16 h1 = __float2bfloat16(v.y * scale);
    __hip_bfloat16 h2 = __float2bfloat16(v.z * scale);
    __hip_bfloat16 h3 = __float2bfloat16(v.w * scale);
    ushort4 o;
    o.x = *(u16*)&h0; o.y = *(u16*)&h1; o.z = *(u16*)&h2; o.w = *(u16*)&h3;
    ((ushort4*)fb)[row * 64 + l] = o;
    if (l == 0) atomicAdd(&hist[lab[row]], 1);
}

__device__ __forceinline__ void gld16(const void* g, void* l) {
    __builtin_amdgcn_global_load_lds((const __attribute__((address_space(1))) u32*)g,
                                     (__attribute__((address_space(3))) u32*)l, 16, 0, 0);
}

// fused sim + row-reduction. grid (64, 16), block 256 (4 waves); wave owns 32 rows.
__launch_bounds__(256, 4)
__global__ void k_main(const __hip_bfloat16* __restrict__ fb,
                       const int* __restrict__ lab,
                       float* __restrict__ SE, float* __restrict__ SP) {
    __shared__ __align__(16) char ldsB[BN * DD * 2];  // 32 KB, XOR-swizzled
    __shared__ int ldsLab[CPS];                       // 2 KB col labels
    const int tid = threadIdx.x;
    const int w = tid >> 6;
    const int l = tid & 63;
    const int l15 = l & 15, lg = l >> 4;
    const int rb = blockIdx.x, sp = blockIdx.y;
    const int wbase = rb * BM + w * 32;
    const int col0 = sp * CPS;

    // stage this split's column labels once
    ldsLab[tid] = lab[col0 + tid];
    ldsLab[tid + 256] = lab[col0 + 256 + tid];

    // A fragments in registers: rows wbase + m*16 + l15, k = kk*32 + lg*8 + [0..7]
    s8v a[2][8];
    #pragma unroll
    for (int m = 0; m < 2; m++)
        #pragma unroll
        for (int kk = 0; kk < 8; kk++)
            a[m][kk] = *(const s8v*)(fb + (wbase + m * 16 + l15) * DD + kk * 32 + lg * 8);

    // labels of the 8 rows this lane accumulates
    int labr[8];
    #pragma unroll
    for (int m = 0; m < 2; m++)
        #pragma unroll
        for (int r = 0; r < 4; r++)
            labr[m * 4 + r] = lab[wbase + m * 16 + lg * 4 + r];

    float sE[8], sPp[8];
    #pragma unroll
    for (int i = 0; i < 8; i++) { sE[i] = 0.f; sPp[i] = 0.f; }

    auto run = [&](auto diagC) {
        constexpr bool DIAG = decltype(diagC)::value;
        for (int it = 0; it < NITER; it++) {
            const int cb = col0 + it * BN;
            __syncthreads();   // previous iter's LDS reads done before overwrite
            // stage B tile via global_load_lds: linear LDS dest, inverse-swizzled source
            const char* gt = (const char*)fb + (size_t)cb * (DD * 2);
            #pragma unroll
            for (int i = 0; i < 8; i++) {
                const int x = w * 8192 + i * 1024 + (l << 4);   // linear LDS byte offset
                const int br = x >> 9;
                const int inrow = x & 511;
                gld16(gt + br * 512 + (inrow ^ ((br & 7) << 4)),
                      ldsB + (w * 8192 + i * 1024));
            }
            __syncthreads();   // compiler drains vmcnt before barrier

            f4v acc[2][4];
            #pragma unroll
            for (int m = 0; m < 2; m++)
                #pragma unroll
                for (int n = 0; n < 4; n++)
                    acc[m][n] = (f4v){0.f, 0.f, 0.f, 0.f};

            #pragma unroll
            for (int kk = 0; kk < 8; kk++) {
                s8v bfr[4];
                #pragma unroll
                for (int n = 0; n < 4; n++) {
                    const int br = n * 16 + l15;
                    const int ad = (br * 512 + kk * 64 + lg * 16) ^ ((br & 7) << 4);
                    bfr[n] = *(const s8v*)(ldsB + ad);
                }
                #pragma unroll
                for (int m = 0; m < 2; m++)
                    #pragma unroll
                    for (int n = 0; n < 4; n++)
                        acc[m][n] = __builtin_amdgcn_mfma_f32_16x16x32_bf16(a[m][kk], bfr[n], acc[m][n], 0, 0, 0);
            }

            #pragma unroll
            for (int n = 0; n < 4; n++) {
                const int col = cb + n * 16 + l15;
                const int lc = ldsLab[it * BN + n * 16 + l15];
                #pragma unroll
                for (int m = 0; m < 2; m++)
                    #pragma unroll
                    for (int r = 0; r < 4; r++) {
                        const int idx = m * 4 + r;
                        const float logit = fmaf(acc[m][n][r], INV_T, -INV_T);
                        float e = fmaxf(__expf(logit), 1e-8f);
                        bool pos = (lc == labr[idx]);
                        if (DIAG) {
                            const int row = wbase + m * 16 + lg * 4 + r;
                            const bool nself = (row != col);
                            e = nself ? e : 0.f;
                            pos = pos && nself;
                        }
                        sE[idx] += e;
                        sPp[idx] += pos ? logit : 0.f;
                    }
            }
        }
    };
    if ((rb >> 2) == sp) run(std::true_type{}); else run(std::false_type{});

    // reduce across the 16 lanes of each group
    #pragma unroll
    for (int idx = 0; idx < 8; idx++) {
        #pragma unroll
        for (int d = 1; d < 16; d <<= 1) {
            sE[idx]  += __shfl_xor(sE[idx], d, 16);
            sPp[idx] += __shfl_xor(sPp[idx], d, 16);
        }
    }
    if (l15 == 0) {
        #pragma unroll
        for (int idx = 0; idx < 8; idx++) {
            const int row = wbase + (idx >> 2) * 16 + lg * 4 + (idx & 3);
            SE[sp * NB + row] = sE[idx];
            SP[sp * NB + row] = sPp[idx];
        }
    }
}

// per-row finalize (chunk fallback is provably dead: CHUNK=256 > NUM_CLASSES=128,
// pigeonhole => every 256-row chunk contains a same-label pair => has_pos always true)
__global__ void k_rows(const int* __restrict__ lab, const int* __restrict__ hist,
                       const float* __restrict__ SE, const float* __restrict__ SP,
                       float* __restrict__ CL, float* __restrict__ CV) {
    const int t = threadIdx.x;
    const int row = blockIdx.x * 256 + t;
    float se = 0.f, sp_ = 0.f;
    #pragma unroll
    for (int s = 0; s < NSPLIT; s++) {
        se  += SE[s * NB + row];
        sp_ += SP[s * NB + row];
    }
    const int n = hist[lab[row]] - 1;
    const float lse = logf(se + 1e-8f);
    const bool valid = n > 0;
    float loss = valid ? (lse - sp_ / (float)n) : 0.f;
    float vf = valid ? 1.f : 0.f;
    #pragma unroll
    for (int d = 32; d; d >>= 1) { loss += __shfl_xor(loss, d, 64); vf += __shfl_xor(vf, d, 64); }
    __shared__ float pl[4], pv[4];
    if ((t & 63) == 0) { pl[t >> 6] = loss; pv[t >> 6] = vf; }
    __syncthreads();
    if (t == 0) {
        CL[blockIdx.x] = pl[0] + pl[1] + pl[2] + pl[3];
        CV[blockIdx.x] = pv[0] + pv[1] + pv[2] + pv[3];
    }
}

__global__ void k_final(const float* __restrict__ CL, const float* __restrict__ CV,
                        float* __restrict__ out) {
    const int t = threadIdx.x;
    float lsum = (t < 32) ? CL[t] : 0.f;
    float vsum = (t < 32) ? CV[t] : 0.f;
    #pragma unroll
    for (int d = 32; d; d >>= 1) { lsum += __shfl_xor(lsum, d, 64); vsum += __shfl_xor(vsum, d, 64); }
    if (t == 0) {
        const float mean = lsum / (vsum + 1e-8f);
        out[0] = mean;   // loss (reduction == 'mean')
        out[1] = vsum;   // total_pairs
        out[2] = mean;   // mean_loss
    }
}

extern "C" void kernel_launch(void* const* d_in, const int* in_sizes, int n_in,
                              void* d_out, int out_size, void* d_ws, size_t ws_size,
                              hipStream_t stream) {
    (void)in_sizes; (void)n_in; (void)out_size; (void)ws_size;
    const float* feat = (const float*)d_in[0];
    const int*   lab  = (const int*)d_in[1];
    char* ws = (char*)d_ws;
    __hip_bfloat16* fb = (__hip_bfloat16*)(ws + OFF_FB);
    int*   hist = (int*)(ws + OFF_HIST);
    float* SE = (float*)(ws + OFF_SE);
    float* SP = (float*)(ws + OFF_SP);
    float* CL = (float*)(ws + OFF_CL);
    float* CV = (float*)(ws + OFF_CV);
    float* out = (float*)d_out;

    hipLaunchKernelGGL(k_zero,  dim3(1), dim3(128), 0, stream, hist);
    hipLaunchKernelGGL(k_norm,  dim3(NB / 4), dim3(256), 0, stream, feat, lab, fb, hist);
    hipLaunchKernelGGL(k_main,  dim3(NB / BM, NSPLIT), dim3(256), 0, stream, fb, lab, SE, SP);
    hipLaunchKernelGGL(k_rows,  dim3(NB / 256), dim3(256), 0, stream, lab, hist, SE, SP, CL, CV);
    hipLaunchKernelGGL(k_final, dim3(1), dim3(64), 0, stream, CL, CV, out);
}

// Round 4
// 80.310 us; speedup vs baseline: 1.9879x; 1.9879x over previous
//
#include <hip/hip_runtime.h>
#include <hip/hip_bf16.h>
#include <type_traits>

#define NB 8192
#define DD 256
#define INV_T (1.0f/0.07f)
#define NSPLIT 8
#define BM 256
#define BN 64
#define CPS (NB/NSPLIT)      // 1024 cols per split
#define NITER (CPS/BN)       // 16
#define BUFB (BN*DD*2)       // 32768 bytes per LDS buffer

typedef __attribute__((ext_vector_type(8))) short s8v;   // 8 bf16
typedef __attribute__((ext_vector_type(4))) float f4v;   // 4 f32 acc
typedef unsigned int u32;
typedef unsigned short u16;

// workspace layout (bytes)
#define OFF_FB   0                                  // bf16 normalized features: 4 MB
#define OFF_HIST (4*1024*1024)
#define OFF_SE   (OFF_HIST + 4096)                  // f32 [NSPLIT][NB]
#define OFF_SP   (OFF_SE + NSPLIT*NB*4)
#define OFF_CL   (OFF_SP + NSPLIT*NB*4)             // f32[32]
#define OFF_CV   (OFF_CL + 256)                     // f32[32]

__global__ void k_zero(int* __restrict__ hist) {
    hist[threadIdx.x] = 0;
}

// wave-per-row normalize: grid 2048 x 256 threads (4 waves = 4 rows/block)
__global__ void k_norm(const float* __restrict__ feat, const int* __restrict__ lab,
                       __hip_bfloat16* __restrict__ fb, int* __restrict__ hist) {
    const int t = threadIdx.x;
    const int w = t >> 6, l = t & 63;
    const int row = blockIdx.x * 4 + w;
    const float4 v = ((const float4*)feat)[row * 64 + l];
    float s = v.x * v.x + v.y * v.y + v.z * v.z + v.w * v.w;
    #pragma unroll
    for (int d = 32; d; d >>= 1) s += __shfl_xor(s, d, 64);
    const float scale = 1.0f / fmaxf(sqrtf(s), 1e-12f);
    __hip_bfloat16 h0 = __float2bfloat16(v.x * scale);
    __hip_bfloat16 h1 = __float2bfloat16(v.y * scale);
    __hip_bfloat16 h2 = __float2bfloat16(v.z * scale);
    __hip_bfloat16 h3 = __float2bfloat16(v.w * scale);
    ushort4 o;
    o.x = *(u16*)&h0; o.y = *(u16*)&h1; o.z = *(u16*)&h2; o.w = *(u16*)&h3;
    ((ushort4*)fb)[row * 64 + l] = o;
    if (l == 0) atomicAdd(&hist[lab[row]], 1);
}

// fused sim + row-reduction. grid 256 linear; sp = bid&7 (XCD affinity), rb = bid>>3.
// block = 512 threads (8 waves); wave owns 32 rows; 256 rows x 1024 cols per block.
__launch_bounds__(512, 2)
__global__ void k_main(const __hip_bfloat16* __restrict__ fb,
                       const int* __restrict__ lab,
                       float* __restrict__ SE, float* __restrict__ SP) {
    __shared__ __align__(16) char ldsB[2 * BUFB];  // 2 x 32 KB, XOR-swizzled
    __shared__ int ldsLab[CPS];                    // 4 KB col labels
    const int tid = threadIdx.x;
    const int w = tid >> 6;
    const int l = tid & 63;
    const int l15 = l & 15, lg = l >> 4;
    const int bid = blockIdx.x;
    const int sp = bid & 7, rb = bid >> 3;
    const int wbase = rb * BM + w * 32;
    const int col0 = sp * CPS;

    // stage this split's column labels once
    ldsLab[tid]       = lab[col0 + tid];
    ldsLab[tid + 512] = lab[col0 + 512 + tid];

    // A fragments in registers: rows wbase + m*16 + l15, k = kk*32 + lg*8 + [0..7]
    s8v a[2][8];
    #pragma unroll
    for (int m = 0; m < 2; m++)
        #pragma unroll
        for (int kk = 0; kk < 8; kk++)
            a[m][kk] = *(const s8v*)(fb + (wbase + m * 16 + l15) * DD + kk * 32 + lg * 8);

    // labels of the 8 rows this lane accumulates
    int labr[8];
    #pragma unroll
    for (int m = 0; m < 2; m++)
        #pragma unroll
        for (int r = 0; r < 4; r++)
            labr[m * 4 + r] = lab[wbase + m * 16 + lg * 4 + r];

    float sE[8], sPp[8];
    #pragma unroll
    for (int i = 0; i < 8; i++) { sE[i] = 0.f; sPp[i] = 0.f; }

    // staging: lane-contiguous global load (coalesced), swizzled ds_write
    s8v st[4];
    auto load_tile = [&](int t) {
        const char* gsrc = (const char*)fb + (size_t)(col0 + t * BN) * (DD * 2);
        #pragma unroll
        for (int i = 0; i < 4; i++)
            st[i] = *(const s8v*)(gsrc + tid * 16 + i * 8192);
    };
    auto write_tile = [&](int bufoff) {
        #pragma unroll
        for (int i = 0; i < 4; i++) {
            const int x = tid * 16 + i * 8192;
            const int br = x >> 9, inrow = x & 511;
            *(s8v*)(ldsB + bufoff + (br * 512 | (inrow ^ ((br & 7) << 4)))) = st[i];
        }
    };

    auto run = [&](auto diagC) {
        constexpr bool DIAG = decltype(diagC)::value;
        load_tile(0);
        write_tile(0);
        __syncthreads();
        for (int t = 0; t < NITER; t++) {
            const int curoff = (t & 1) * BUFB;
            if (t + 1 < NITER) load_tile(t + 1);

            f4v acc[2][4];
            #pragma unroll
            for (int m = 0; m < 2; m++)
                #pragma unroll
                for (int n = 0; n < 4; n++)
                    acc[m][n] = (f4v){0.f, 0.f, 0.f, 0.f};

            #pragma unroll
            for (int kk = 0; kk < 8; kk++) {
                s8v bfr[4];
                #pragma unroll
                for (int n = 0; n < 4; n++) {
                    const int br = n * 16 + l15;
                    const int ad = (br * 512 + kk * 64 + lg * 16) ^ ((br & 7) << 4);
                    bfr[n] = *(const s8v*)(ldsB + curoff + ad);
                }
                #pragma unroll
                for (int m = 0; m < 2; m++)
                    #pragma unroll
                    for (int n = 0; n < 4; n++)
                        acc[m][n] = __builtin_amdgcn_mfma_f32_16x16x32_bf16(a[m][kk], bfr[n], acc[m][n], 0, 0, 0);
            }

            const int cb = col0 + t * BN;
            #pragma unroll
            for (int n = 0; n < 4; n++) {
                const int col = cb + n * 16 + l15;
                const int lc = ldsLab[t * BN + n * 16 + l15];
                #pragma unroll
                for (int m = 0; m < 2; m++)
                    #pragma unroll
                    for (int r = 0; r < 4; r++) {
                        const int idx = m * 4 + r;
                        const float logit = fmaf(acc[m][n][r], INV_T, -INV_T);
                        float e = fmaxf(__expf(logit), 1e-8f);
                        bool pos = (lc == labr[idx]);
                        if (DIAG) {
                            const int row = wbase + m * 16 + lg * 4 + r;
                            const bool nself = (row != col);
                            e = nself ? e : 0.f;
                            pos = pos && nself;
                        }
                        sE[idx] += e;
                        sPp[idx] += pos ? logit : 0.f;
                    }
            }

            if (t + 1 < NITER) write_tile(curoff ^ BUFB);
            __syncthreads();
        }
    };
    if ((rb >> 2) == sp) run(std::true_type{}); else run(std::false_type{});

    // reduce across the 16 lanes of each group
    #pragma unroll
    for (int idx = 0; idx < 8; idx++) {
        #pragma unroll
        for (int d = 1; d < 16; d <<= 1) {
            sE[idx]  += __shfl_xor(sE[idx], d, 16);
            sPp[idx] += __shfl_xor(sPp[idx], d, 16);
        }
    }
    if (l15 == 0) {
        #pragma unroll
        for (int idx = 0; idx < 8; idx++) {
            const int row = wbase + (idx >> 2) * 16 + lg * 4 + (idx & 3);
            SE[sp * NB + row] = sE[idx];
            SP[sp * NB + row] = sPp[idx];
        }
    }
}

// per-row finalize (chunk fallback provably dead: CHUNK=256 > NUM_CLASSES=128)
__global__ void k_rows(const int* __restrict__ lab, const int* __restrict__ hist,
                       const float* __restrict__ SE, const float* __restrict__ SP,
                       float* __restrict__ CL, float* __restrict__ CV) {
    const int t = threadIdx.x;
    const int row = blockIdx.x * 256 + t;
    float se = 0.f, sp_ = 0.f;
    #pragma unroll
    for (int s = 0; s < NSPLIT; s++) {
        se  += SE[s * NB + row];
        sp_ += SP[s * NB + row];
    }
    const int n = hist[lab[row]] - 1;
    const float lse = logf(se + 1e-8f);
    const bool valid = n > 0;
    float loss = valid ? (lse - sp_ / (float)n) : 0.f;
    float vf = valid ? 1.f : 0.f;
    #pragma unroll
    for (int d = 32; d; d >>= 1) { loss += __shfl_xor(loss, d, 64); vf += __shfl_xor(vf, d, 64); }
    __shared__ float pl[4], pv[4];
    if ((t & 63) == 0) { pl[t >> 6] = loss; pv[t >> 6] = vf; }
    __syncthreads();
    if (t == 0) {
        CL[blockIdx.x] = pl[0] + pl[1] + pl[2] + pl[3];
        CV[blockIdx.x] = pv[0] + pv[1] + pv[2] + pv[3];
    }
}

__global__ void k_final(const float* __restrict__ CL, const float* __restrict__ CV,
                        float* __restrict__ out) {
    const int t = threadIdx.x;
    float lsum = (t < 32) ? CL[t] : 0.f;
    float vsum = (t < 32) ? CV[t] : 0.f;
    #pragma unroll
    for (int d = 32; d; d >>= 1) { lsum += __shfl_xor(lsum, d, 64); vsum += __shfl_xor(vsum, d, 64); }
    if (t == 0) {
        const float mean = lsum / (vsum + 1e-8f);
        out[0] = mean;   // loss (reduction == 'mean')
        out[1] = vsum;   // total_pairs
        out[2] = mean;   // mean_loss
    }
}

extern "C" void kernel_launch(void* const* d_in, const int* in_sizes, int n_in,
                              void* d_out, int out_size, void* d_ws, size_t ws_size,
                              hipStream_t stream) {
    (void)in_sizes; (void)n_in; (void)out_size; (void)ws_size;
    const float* feat = (const float*)d_in[0];
    const int*   lab  = (const int*)d_in[1];
    char* ws = (char*)d_ws;
    __hip_bfloat16* fb = (__hip_bfloat16*)(ws + OFF_FB);
    int*   hist = (int*)(ws + OFF_HIST);
    float* SE = (float*)(ws + OFF_SE);
    float* SP = (float*)(ws + OFF_SP);
    float* CL = (float*)(ws + OFF_CL);
    float* CV = (float*)(ws + OFF_CV);
    float* out = (float*)d_out;

    hipLaunchKernelGGL(k_zero,  dim3(1), dim3(128), 0, stream, hist);
    hipLaunchKernelGGL(k_norm,  dim3(NB / 4), dim3(256), 0, stream, feat, lab, fb, hist);
    hipLaunchKernelGGL(k_main,  dim3(NB / BM * NSPLIT), dim3(512), 0, stream, fb, lab, SE, SP);
    hipLaunchKernelGGL(k_rows,  dim3(NB / 256), dim3(256), 0, stream, lab, hist, SE, SP, CL, CV);
    hipLaunchKernelGGL(k_final, dim3(1), dim3(64), 0, stream, CL, CV, out);
}

// Round 5
// 71.673 us; speedup vs baseline: 2.2275x; 1.1205x over previous
//
#include <hip/hip_runtime.h>
#include <hip/hip_bf16.h>
#include <type_traits>

#define NB 8192
#define DD 256
#define INV_T (1.0f/0.07f)
#define LOG2E 1.4426950408889634f
#define LN2   0.6931471805599453f
#define K1    (INV_T*LOG2E)
#define NSPLIT 8
#define BM 128
#define BN 64
#define CPS (NB/NSPLIT)      // 1024 cols per split
#define NITER (CPS/BN)       // 16
#define BUFB (BN*DD*2)       // 32768 bytes per LDS buffer

typedef __attribute__((ext_vector_type(8))) short s8v;   // 8 bf16
typedef __attribute__((ext_vector_type(4))) float f4v;   // 4 f32 acc
typedef unsigned int u32;
typedef unsigned short u16;

// workspace layout (bytes)
#define OFF_FB   0                                  // bf16 normalized features: 4 MB
#define OFF_SE   (4*1024*1024)                      // f32 [NSPLIT][NB]
#define OFF_SP   (OFF_SE + NSPLIT*NB*4)
#define OFF_CL   (OFF_SP + NSPLIT*NB*4)             // f32[32]
#define OFF_CV   (OFF_CL + 256)                     // f32[32]
#define OFF_CNT  (OFF_CV + 256)                     // int[1]

// wave-per-row normalize: grid 2048 x 256 threads; block 0 zeros the finish counter
__global__ void k_norm(const float* __restrict__ feat,
                       __hip_bfloat16* __restrict__ fb, int* __restrict__ cnt) {
    if (blockIdx.x == 0 && threadIdx.x == 0) *cnt = 0;
    const int t = threadIdx.x;
    const int w = t >> 6, l = t & 63;
    const int row = blockIdx.x * 4 + w;
    const float4 v = ((const float4*)feat)[row * 64 + l];
    float s = v.x * v.x + v.y * v.y + v.z * v.z + v.w * v.w;
    #pragma unroll
    for (int d = 32; d; d >>= 1) s += __shfl_xor(s, d, 64);
    const float scale = 1.0f / fmaxf(sqrtf(s), 1e-12f);
    __hip_bfloat16 h0 = __float2bfloat16(v.x * scale);
    __hip_bfloat16 h1 = __float2bfloat16(v.y * scale);
    __hip_bfloat16 h2 = __float2bfloat16(v.z * scale);
    __hip_bfloat16 h3 = __float2bfloat16(v.w * scale);
    ushort4 o;
    o.x = *(u16*)&h0; o.y = *(u16*)&h1; o.z = *(u16*)&h2; o.w = *(u16*)&h3;
    ((ushort4*)fb)[row * 64 + l] = o;
}

// fused sim + row-reduction. grid 512 linear; sp = bid&7 (XCD affinity), rb = bid>>3.
// block = 256 threads (4 waves); wave owns 32 rows; 128 rows x 1024 cols per block.
// 2 blocks/CU -> two independent barrier domains overlap LDS/MFMA/VALU phases.
__launch_bounds__(256, 2)
__global__ void k_main(const __hip_bfloat16* __restrict__ fb,
                       const int* __restrict__ lab,
                       float* __restrict__ SE, float* __restrict__ SP) {
    __shared__ __align__(16) char ldsB[2 * BUFB];  // 2 x 32 KB, XOR-swizzled
    __shared__ int ldsLab[CPS];                    // 4 KB col labels
    const int tid = threadIdx.x;
    const int l = tid & 63;
    const int l15 = l & 15, lg = l >> 4;
    const int bid = blockIdx.x;
    const int sp = bid & 7, rb = bid >> 3;
    const int wbase = rb * BM + (tid >> 6) * 32;
    const int col0 = sp * CPS;

    // stage this split's column labels once
    #pragma unroll
    for (int i = 0; i < 4; i++)
        ldsLab[tid + i * 256] = lab[col0 + tid + i * 256];

    // A fragments in registers: rows wbase + m*16 + l15, k = kk*32 + lg*8 + [0..7]
    s8v a[2][8];
    #pragma unroll
    for (int m = 0; m < 2; m++)
        #pragma unroll
        for (int kk = 0; kk < 8; kk++)
            a[m][kk] = *(const s8v*)(fb + (wbase + m * 16 + l15) * DD + kk * 32 + lg * 8);

    // labels of the 8 rows this lane accumulates
    int labr[8];
    #pragma unroll
    for (int m = 0; m < 2; m++)
        #pragma unroll
        for (int r = 0; r < 4; r++)
            labr[m * 4 + r] = lab[wbase + m * 16 + lg * 4 + r];

    float sE[8], sPp[8];
    #pragma unroll
    for (int i = 0; i < 8; i++) { sE[i] = 0.f; sPp[i] = 0.f; }

    // staging: lane-contiguous global load (coalesced), swizzled ds_write
    s8v st[8];
    auto load_tile = [&](int t) {
        const char* gsrc = (const char*)fb + (size_t)(col0 + t * BN) * (DD * 2);
        #pragma unroll
        for (int i = 0; i < 8; i++)
            st[i] = *(const s8v*)(gsrc + tid * 16 + i * 4096);
    };
    auto write_tile = [&](int bufoff) {
        #pragma unroll
        for (int i = 0; i < 8; i++) {
            const int x = tid * 16 + i * 4096;
            const int br = x >> 9, inrow = x & 511;
            *(s8v*)(ldsB + bufoff + (br * 512 | (inrow ^ ((br & 7) << 4)))) = st[i];
        }
    };

    auto run = [&](auto diagC) {
        constexpr bool DIAG = decltype(diagC)::value;
        load_tile(0);
        write_tile(0);
        __syncthreads();
        for (int t = 0; t < NITER; t++) {
            const int curoff = (t & 1) * BUFB;
            if (t + 1 < NITER) load_tile(t + 1);

            f4v acc[2][4];
            #pragma unroll
            for (int m = 0; m < 2; m++)
                #pragma unroll
                for (int n = 0; n < 4; n++)
                    acc[m][n] = (f4v){0.f, 0.f, 0.f, 0.f};

            #pragma unroll
            for (int kk = 0; kk < 8; kk++) {
                s8v bfr[4];
                #pragma unroll
                for (int n = 0; n < 4; n++) {
                    const int br = n * 16 + l15;
                    const int ad = (br * 512 + kk * 64 + lg * 16) ^ ((br & 7) << 4);
                    bfr[n] = *(const s8v*)(ldsB + curoff + ad);
                }
                #pragma unroll
                for (int m = 0; m < 2; m++)
                    #pragma unroll
                    for (int n = 0; n < 4; n++)
                        acc[m][n] = __builtin_amdgcn_mfma_f32_16x16x32_bf16(a[m][kk], bfr[n], acc[m][n], 0, 0, 0);
            }

            const int cb = col0 + t * BN;
            #pragma unroll
            for (int n = 0; n < 4; n++) {
                const int col = cb + n * 16 + l15;
                const int lc = ldsLab[t * BN + n * 16 + l15];
                #pragma unroll
                for (int m = 0; m < 2; m++)
                    #pragma unroll
                    for (int r = 0; r < 4; r++) {
                        const int idx = m * 4 + r;
                        // logit in log2 units: (sim-1)/T * log2(e)
                        const float lg2 = fmaf(acc[m][n][r], K1, -K1);
                        float e = fmaxf(exp2f(lg2), 1e-8f);
                        bool pos = (lc == labr[idx]);
                        if (DIAG) {
                            const int row = wbase + m * 16 + lg * 4 + r;
                            const bool nself = (row != col);
                            e = nself ? e : 0.f;
                            pos = pos && nself;
                        }
                        sE[idx] += e;
                        sPp[idx] += pos ? lg2 : 0.f;
                    }
            }

            if (t + 1 < NITER) write_tile(curoff ^ BUFB);
            __syncthreads();
        }
    };
    if ((rb >> 3) == sp) run(std::true_type{}); else run(std::false_type{});

    // reduce across the 16 lanes of each group
    #pragma unroll
    for (int idx = 0; idx < 8; idx++) {
        #pragma unroll
        for (int d = 1; d < 16; d <<= 1) {
            sE[idx]  += __shfl_xor(sE[idx], d, 16);
            sPp[idx] += __shfl_xor(sPp[idx], d, 16);
        }
    }
    if (l15 == 0) {
        #pragma unroll
        for (int idx = 0; idx < 8; idx++) {
            const int row = wbase + (idx >> 2) * 16 + lg * 4 + (idx & 3);
            SE[sp * NB + row] = sE[idx];
            SP[sp * NB + row] = sPp[idx];
        }
    }
}

// per-row finalize; 32 blocks of 256 (one 256-row chunk each).
// Per-block label histogram (labels are L2-resident, 32KB). Chunk fallback provably
// dead: CHUNK=256 > NUM_CLASSES=128 => every chunk has a positive pair.
// Last block (fenced counter) reduces the 32 partials and writes the 3 outputs.
__global__ void k_rows(const int* __restrict__ lab,
                       const float* __restrict__ SE, const float* __restrict__ SP,
                       float* __restrict__ CL, float* __restrict__ CV,
                       int* __restrict__ cnt, float* __restrict__ out) {
    __shared__ int h[128];
    const int t = threadIdx.x;
    if (t < 128) h[t] = 0;
    __syncthreads();
    #pragma unroll
    for (int i = 0; i < 32; i++)
        atomicAdd(&h[lab[t + i * 256]], 1);
    __syncthreads();

    const int row = blockIdx.x * 256 + t;
    float se = 0.f, sp_ = 0.f;
    #pragma unroll
    for (int s = 0; s < NSPLIT; s++) {
        se  += SE[s * NB + row];
        sp_ += SP[s * NB + row];
    }
    const int n = h[lab[row]] - 1;
    const float lse = logf(se + 1e-8f);
    const bool valid = n > 0;
    float loss = valid ? (lse - sp_ * LN2 / (float)n) : 0.f;
    float vf = valid ? 1.f : 0.f;
    #pragma unroll
    for (int d = 32; d; d >>= 1) { loss += __shfl_xor(loss, d, 64); vf += __shfl_xor(vf, d, 64); }
    __shared__ float pl[4], pv[4];
    __shared__ int isLast;
    if ((t & 63) == 0) { pl[t >> 6] = loss; pv[t >> 6] = vf; }
    __syncthreads();
    if (t == 0) {
        CL[blockIdx.x] = pl[0] + pl[1] + pl[2] + pl[3];
        CV[blockIdx.x] = pv[0] + pv[1] + pv[2] + pv[3];
        __threadfence();                       // release CL/CV
        isLast = (atomicAdd(cnt, 1) == 31);
    }
    __syncthreads();
    if (isLast) {
        __threadfence();                       // acquire others' CL/CV
        float lsum = (t < 32) ? CL[t] : 0.f;
        float vsum = (t < 32) ? CV[t] : 0.f;
        #pragma unroll
        for (int d = 32; d; d >>= 1) { lsum += __shfl_xor(lsum, d, 64); vsum += __shfl_xor(vsum, d, 64); }
        if (t == 0) {
            const float mean = lsum / (vsum + 1e-8f);
            out[0] = mean;   // loss (reduction == 'mean')
            out[1] = vsum;   // total_pairs
            out[2] = mean;   // mean_loss
        }
    }
}

extern "C" void kernel_launch(void* const* d_in, const int* in_sizes, int n_in,
                              void* d_out, int out_size, void* d_ws, size_t ws_size,
                              hipStream_t stream) {
    (void)in_sizes; (void)n_in; (void)out_size; (void)ws_size;
    const float* feat = (const float*)d_in[0];
    const int*   lab  = (const int*)d_in[1];
    char* ws = (char*)d_ws;
    __hip_bfloat16* fb = (__hip_bfloat16*)(ws + OFF_FB);
    float* SE = (float*)(ws + OFF_SE);
    float* SP = (float*)(ws + OFF_SP);
    float* CL = (float*)(ws + OFF_CL);
    float* CV = (float*)(ws + OFF_CV);
    int*   cnt = (int*)(ws + OFF_CNT);
    float* out = (float*)d_out;

    hipLaunchKernelGGL(k_norm, dim3(NB / 4), dim3(256), 0, stream, feat, fb, cnt);
    hipLaunchKernelGGL(k_main, dim3(NB / BM * NSPLIT), dim3(256), 0, stream, fb, lab, SE, SP);
    hipLaunchKernelGGL(k_rows, dim3(NB / 256), dim3(256), 0, stream, lab, SE, SP, CL, CV, cnt, out);
}

// Round 6
// 70.735 us; speedup vs baseline: 2.2570x; 1.0133x over previous
//
#include <hip/hip_runtime.h>
#include <hip/hip_bf16.h>
#include <type_traits>

#define NB 8192
#define DD 256
#define INV_T (1.0f/0.07f)
#define LOG2E 1.4426950408889634f
#define K1    (INV_T*LOG2E)          // logit (log2 units) = acc*K1 - K1
#define CEXP  6.2087204553847255e-7f // exp(-1/0.07): folds the -K1 term into se
#define NSPLIT 8
#define BM 256
#define BN 64
#define CPS (NB/NSPLIT)      // 1024 cols per split
#define NITER (CPS/BN)       // 16
#define BUFB (BN*DD*2)       // 32768 bytes per LDS buffer

typedef __attribute__((ext_vector_type(8))) short s8v;   // 8 bf16
typedef __attribute__((ext_vector_type(4))) float f4v;   // 4 f32 acc
typedef unsigned int u32;
typedef unsigned short u16;

// workspace layout (bytes)
#define OFF_FB   0                                  // bf16 normalized features: 4 MB
#define OFF_SE   (4*1024*1024)                      // f32 [NSPLIT][NB]
#define OFF_SP   (OFF_SE + NSPLIT*NB*4)
#define OFF_CL   (OFF_SP + NSPLIT*NB*4)             // f32[32]
#define OFF_CV   (OFF_CL + 256)                     // f32[32]
#define OFF_CNT  (OFF_CV + 256)                     // int[1]

// wave-per-row normalize: grid 2048 x 256 threads; block 0 zeros the finish counter
__global__ void k_norm(const float* __restrict__ feat,
                       __hip_bfloat16* __restrict__ fb, int* __restrict__ cnt) {
    if (blockIdx.x == 0 && threadIdx.x == 0) *cnt = 0;
    const int t = threadIdx.x;
    const int w = t >> 6, l = t & 63;
    const int row = blockIdx.x * 4 + w;
    const float4 v = ((const float4*)feat)[row * 64 + l];
    float s = v.x * v.x + v.y * v.y + v.z * v.z + v.w * v.w;
    #pragma unroll
    for (int d = 32; d; d >>= 1) s += __shfl_xor(s, d, 64);
    const float scale = 1.0f / fmaxf(sqrtf(s), 1e-12f);
    __hip_bfloat16 h0 = __float2bfloat16(v.x * scale);
    __hip_bfloat16 h1 = __float2bfloat16(v.y * scale);
    __hip_bfloat16 h2 = __float2bfloat16(v.z * scale);
    __hip_bfloat16 h3 = __float2bfloat16(v.w * scale);
    ushort4 o;
    o.x = *(u16*)&h0; o.y = *(u16*)&h1; o.z = *(u16*)&h2; o.w = *(u16*)&h3;
    ((ushort4*)fb)[row * 64 + l] = o;
}

// fused sim + row-reduction. grid 256 linear; sp = bid&7 (XCD affinity), rb = bid>>3.
// block = 512 threads (8 waves); wave owns 32 rows; 256 rows x 1024 cols per block.
// Per iter: MFMA pass (n=0,1) -> issue MFMA pass (n=2,3) -> epilogue(0,1) VALU
// overlaps the drain of pass 2 -> epilogue(2,3).
__launch_bounds__(512)
__global__ void k_main(const __hip_bfloat16* __restrict__ fb,
                       const int* __restrict__ lab,
                       float* __restrict__ SE, float* __restrict__ SP) {
    __shared__ __align__(16) char ldsB[2 * BUFB];  // 2 x 32 KB, XOR-swizzled
    __shared__ int ldsLab[CPS];                    // 4 KB col labels
    const int tid = threadIdx.x;
    const int l = tid & 63;
    const int l15 = l & 15, lg = l >> 4;
    const int bid = blockIdx.x;
    const int sp = bid & 7, rb = bid >> 3;
    const int wbase = rb * BM + (tid >> 6) * 32;
    const int col0 = sp * CPS;

    // stage this split's column labels once
    ldsLab[tid]       = lab[col0 + tid];
    ldsLab[tid + 512] = lab[col0 + 512 + tid];

    // A fragments in registers: rows wbase + m*16 + l15, k = kk*32 + lg*8 + [0..7]
    s8v a[2][8];
    #pragma unroll
    for (int m = 0; m < 2; m++)
        #pragma unroll
        for (int kk = 0; kk < 8; kk++)
            a[m][kk] = *(const s8v*)(fb + (wbase + m * 16 + l15) * DD + kk * 32 + lg * 8);

    // labels of the 8 rows this lane accumulates
    int labr[8];
    #pragma unroll
    for (int m = 0; m < 2; m++)
        #pragma unroll
        for (int r = 0; r < 4; r++)
            labr[m * 4 + r] = lab[wbase + m * 16 + lg * 4 + r];

    float sE[8], sPa[8];
    #pragma unroll
    for (int i = 0; i < 8; i++) { sE[i] = 0.f; sPa[i] = 0.f; }

    // staging: lane-contiguous global load (coalesced), swizzled ds_write
    s8v st[4];
    auto load_tile = [&](int t) {
        const char* gsrc = (const char*)fb + (size_t)(col0 + t * BN) * (DD * 2);
        #pragma unroll
        for (int i = 0; i < 4; i++)
            st[i] = *(const s8v*)(gsrc + tid * 16 + i * 8192);
    };
    auto write_tile = [&](int bufoff) {
        #pragma unroll
        for (int i = 0; i < 4; i++) {
            const int x = tid * 16 + i * 8192;
            const int br = x >> 9, inrow = x & 511;
            *(s8v*)(ldsB + bufoff + (br * 512 | (inrow ^ ((br & 7) << 4)))) = st[i];
        }
    };

    auto run = [&](auto diagC) {
        constexpr bool DIAG = decltype(diagC)::value;
        load_tile(0);
        write_tile(0);
        __syncthreads();
        for (int t = 0; t < NITER; t++) {
            const int curoff = (t & 1) * BUFB;
            if (t + 1 < NITER) load_tile(t + 1);

            // hoist this tile's column labels for the epilogue
            int lc[4];
            #pragma unroll
            for (int n = 0; n < 4; n++)
                lc[n] = ldsLab[t * BN + n * 16 + l15];

            f4v acc[2][4];
            #pragma unroll
            for (int m = 0; m < 2; m++)
                #pragma unroll
                for (int n = 0; n < 4; n++)
                    acc[m][n] = (f4v){0.f, 0.f, 0.f, 0.f};

            // pass 1: n = 0,1
            #pragma unroll
            for (int kk = 0; kk < 8; kk++) {
                s8v b0, b1;
                {
                    const int br0 = 0 * 16 + l15, br1 = 1 * 16 + l15;
                    b0 = *(const s8v*)(ldsB + curoff + ((br0 * 512 + kk * 64 + lg * 16) ^ ((br0 & 7) << 4)));
                    b1 = *(const s8v*)(ldsB + curoff + ((br1 * 512 + kk * 64 + lg * 16) ^ ((br1 & 7) << 4)));
                }
                acc[0][0] = __builtin_amdgcn_mfma_f32_16x16x32_bf16(a[0][kk], b0, acc[0][0], 0, 0, 0);
                acc[1][0] = __builtin_amdgcn_mfma_f32_16x16x32_bf16(a[1][kk], b0, acc[1][0], 0, 0, 0);
                acc[0][1] = __builtin_amdgcn_mfma_f32_16x16x32_bf16(a[0][kk], b1, acc[0][1], 0, 0, 0);
                acc[1][1] = __builtin_amdgcn_mfma_f32_16x16x32_bf16(a[1][kk], b1, acc[1][1], 0, 0, 0);
            }
            // pass 2: n = 2,3 (issued before epilogue(0,1) so its MFMAs drain under VALU)
            #pragma unroll
            for (int kk = 0; kk < 8; kk++) {
                s8v b2, b3;
                {
                    const int br2 = 2 * 16 + l15, br3 = 3 * 16 + l15;
                    b2 = *(const s8v*)(ldsB + curoff + ((br2 * 512 + kk * 64 + lg * 16) ^ ((br2 & 7) << 4)));
                    b3 = *(const s8v*)(ldsB + curoff + ((br3 * 512 + kk * 64 + lg * 16) ^ ((br3 & 7) << 4)));
                }
                acc[0][2] = __builtin_amdgcn_mfma_f32_16x16x32_bf16(a[0][kk], b2, acc[0][2], 0, 0, 0);
                acc[1][2] = __builtin_amdgcn_mfma_f32_16x16x32_bf16(a[1][kk], b2, acc[1][2], 0, 0, 0);
                acc[0][3] = __builtin_amdgcn_mfma_f32_16x16x32_bf16(a[0][kk], b3, acc[0][3], 0, 0, 0);
                acc[1][3] = __builtin_amdgcn_mfma_f32_16x16x32_bf16(a[1][kk], b3, acc[1][3], 0, 0, 0);
            }

            const int cb = col0 + t * BN;
            auto ep = [&](int n) {
                #pragma unroll
                for (int m = 0; m < 2; m++)
                    #pragma unroll
                    for (int r = 0; r < 4; r++) {
                        const int idx = m * 4 + r;
                        const float v = acc[m][n][r];
                        float e = exp2f(v * K1);          // unscaled: true e = CEXP * this
                        bool pos = (lc[n] == labr[idx]);
                        if (DIAG) {
                            const int row = wbase + m * 16 + lg * 4 + r;
                            const int col = cb + n * 16 + l15;
                            const bool nself = (row != col);
                            e = nself ? e : 0.f;
                            pos = pos && nself;
                        }
                        sE[idx] += e;
                        sPa[idx] += pos ? v : 0.f;        // raw sim; log-term folded in k_rows
                    }
            };
            ep(0); ep(1);   // overlaps pass-2 MFMA drain
            ep(2); ep(3);

            if (t + 1 < NITER) write_tile(curoff ^ BUFB);
            __syncthreads();
        }
    };
    if ((rb >> 2) == sp) run(std::true_type{}); else run(std::false_type{});

    // reduce across the 16 lanes of each group
    #pragma unroll
    for (int idx = 0; idx < 8; idx++) {
        #pragma unroll
        for (int d = 1; d < 16; d <<= 1) {
            sE[idx]  += __shfl_xor(sE[idx], d, 16);
            sPa[idx] += __shfl_xor(sPa[idx], d, 16);
        }
    }
    if (l15 == 0) {
        #pragma unroll
        for (int idx = 0; idx < 8; idx++) {
            const int row = wbase + (idx >> 2) * 16 + lg * 4 + (idx & 3);
            SE[sp * NB + row] = sE[idx];
            SP[sp * NB + row] = sPa[idx];
        }
    }
}

// per-row finalize; 32 blocks of 256 (one 256-row chunk each).
// loss_row = log(se*CEXP + 1e-8) - (spa - n)*INV_T/n   [spa = sum_pos sim]
// Chunk fallback provably dead: CHUNK=256 > NUM_CLASSES=128.
__global__ void k_rows(const int* __restrict__ lab,
                       const float* __restrict__ SE, const float* __restrict__ SP,
                       float* __restrict__ CL, float* __restrict__ CV,
                       int* __restrict__ cnt, float* __restrict__ out) {
    __shared__ int h[128];
    const int t = threadIdx.x;
    if (t < 128) h[t] = 0;
    __syncthreads();
    #pragma unroll
    for (int i = 0; i < 32; i++)
        atomicAdd(&h[lab[t + i * 256]], 1);
    __syncthreads();

    const int row = blockIdx.x * 256 + t;
    float se = 0.f, spa = 0.f;
    #pragma unroll
    for (int s = 0; s < NSPLIT; s++) {
        se  += SE[s * NB + row];
        spa += SP[s * NB + row];
    }
    const int n = h[lab[row]] - 1;
    const float lse = logf(se * CEXP + 1e-8f);
    const bool valid = n > 0;
    float loss = valid ? (lse - (spa - (float)n) * INV_T / (float)n) : 0.f;
    float vf = valid ? 1.f : 0.f;
    #pragma unroll
    for (int d = 32; d; d >>= 1) { loss += __shfl_xor(loss, d, 64); vf += __shfl_xor(vf, d, 64); }
    __shared__ float pl[4], pv[4];
    __shared__ int isLast;
    if ((t & 63) == 0) { pl[t >> 6] = loss; pv[t >> 6] = vf; }
    __syncthreads();
    if (t == 0) {
        CL[blockIdx.x] = pl[0] + pl[1] + pl[2] + pl[3];
        CV[blockIdx.x] = pv[0] + pv[1] + pv[2] + pv[3];
        __threadfence();                       // release CL/CV
        isLast = (atomicAdd(cnt, 1) == 31);
    }
    __syncthreads();
    if (isLast) {
        __threadfence();                       // acquire others' CL/CV
        float lsum = (t < 32) ? CL[t] : 0.f;
        float vsum = (t < 32) ? CV[t] : 0.f;
        #pragma unroll
        for (int d = 32; d; d >>= 1) { lsum += __shfl_xor(lsum, d, 64); vsum += __shfl_xor(vsum, d, 64); }
        if (t == 0) {
            const float mean = lsum / (vsum + 1e-8f);
            out[0] = mean;   // loss (reduction == 'mean')
            out[1] = vsum;   // total_pairs
            out[2] = mean;   // mean_loss
        }
    }
}

extern "C" void kernel_launch(void* const* d_in, const int* in_sizes, int n_in,
                              void* d_out, int out_size, void* d_ws, size_t ws_size,
                              hipStream_t stream) {
    (void)in_sizes; (void)n_in; (void)out_size; (void)ws_size;
    const float* feat = (const float*)d_in[0];
    const int*   lab  = (const int*)d_in[1];
    char* ws = (char*)d_ws;
    __hip_bfloat16* fb = (__hip_bfloat16*)(ws + OFF_FB);
    float* SE = (float*)(ws + OFF_SE);
    float* SP = (float*)(ws + OFF_SP);
    float* CL = (float*)(ws + OFF_CL);
    float* CV = (float*)(ws + OFF_CV);
    int*   cnt = (int*)(ws + OFF_CNT);
    float* out = (float*)d_out;

    hipLaunchKernelGGL(k_norm, dim3(NB / 4), dim3(256), 0, stream, feat, fb, cnt);
    hipLaunchKernelGGL(k_main, dim3(NB / BM * NSPLIT), dim3(512), 0, stream, fb, lab, SE, SP);
    hipLaunchKernelGGL(k_rows, dim3(NB / 256), dim3(256), 0, stream, lab, SE, SP, CL, CV, cnt, out);
}